// Round 3
// baseline (1995.477 us; speedup 1.0000x reference)
//
#include <hip/hip_runtime.h>

typedef unsigned short u16;
typedef unsigned int u32;

#define B_N 4096
#define S_N 256
#define T_N 50
#define H_N 256

// d_ws float-index layout (all fp32 after conversion)
#define W1F 0
#define W2F 65536
#define W3F 131072
#define W4F 196608
#define B1F 197120
#define B2F 197376
#define B3F 197632
#define B4F 197888
#define CVT_N 197890
#define FLAGI 198656   // int slot (aliased into the float ws)

__device__ __forceinline__ float bf2f(u16 h) { return __uint_as_float(((u32)h) << 16); }
__device__ __forceinline__ u16 f2bf(float f) {
  u32 x = __float_as_uint(f);
  return (u16)((x + 0x7fffu + ((x >> 16) & 1u)) >> 16);
}
__device__ __forceinline__ float ld_f(const void* p, size_t i, int isbf) {
  return isbf ? bf2f(((const u16*)p)[i]) : ((const float*)p)[i];
}

// bf16 x values are U(0,1): every even-index u16 <= 0x3F80 (~100%).
// fp32 x: even u16s are low mantissa halves: ~25% below 0x3F80.
__global__ void detect_dtype(const u16* __restrict__ x, int* __restrict__ flag) {
  __shared__ int cnt[256];
  int c = 0;
  for (int i = threadIdx.x; i < 4096; i += 256) c += (x[2 * i] <= 0x3F80u) ? 1 : 0;
  cnt[threadIdx.x] = c;
  __syncthreads();
  if (threadIdx.x == 0) {
    int tot = 0;
    for (int i = 0; i < 256; i++) tot += cnt[i];
    flag[0] = (tot > 3000) ? 1 : 0;
  }
}

// Up-convert all weights/biases to fp32 in ws (exact; bf16->fp32 is lossless).
__global__ void convert_inputs(const void* w1, const void* w2, const void* w3,
                               const void* w4, const void* b1, const void* b2,
                               const void* b3, const void* b4, float* __restrict__ ws) {
  const int isbf = ((const int*)ws)[FLAGI];
  int i = blockIdx.x * 256 + threadIdx.x;
  if (i >= CVT_N) return;
  float v;
  if (i < 196608) {
    const void* src = (i < 65536) ? w1 : (i < 131072 ? w2 : w3);
    v = ld_f(src, (size_t)(i & 65535), isbf);
  } else if (i < 197120) v = ld_f(w4, (size_t)(i - W4F), isbf);
  else if (i < 197376) v = ld_f(b1, (size_t)(i - B1F), isbf);
  else if (i < 197632) v = ld_f(b2, (size_t)(i - B2F), isbf);
  else if (i < 197888) v = ld_f(b3, (size_t)(i - B3F), isbf);
  else v = ld_f(b4, (size_t)(i - B4F), isbf);
  ws[i] = v;
}

// One block per batch element; all 4 LIF layers fused. GEMMs replicate
// OpenBLAS sgemm's per-element arithmetic EXACTLY: a single ascending-k
// fused-FMA chain in fp32 (K=256 fits one kc panel; BLAS vectorizes over
// M/N only, so each C element is a serial vfmadd chain from zero).
// Elementwise LIF scan replicates np fp32 ops (contraction-safe forms).
__global__ __launch_bounds__(256) void snn_f32(
    const void* __restrict__ x, const float* __restrict__ ws, void* __restrict__ out) {
  __shared__ float Af[S_N][52];    // A[s][t]: layer input (x, then spikes), fp32
  __shared__ float zs[52][260];    // GEMM result z[t][h]
  __shared__ float z4[T_N][2];

  const int b = blockIdx.x;
  const int tid = threadIdx.x;
  const int isbf = ((const int*)ws)[FLAGI];
  const int t0 = tid >> 4;          // 16 t-tiles of 4
  const int h0 = (tid & 15) * 4;    // h within 64-group; + off*64

  // ---- stage x -> Af[s][t] (thread = source row s) ----
  {
    const size_t base = ((size_t)b * S_N + tid) * T_N;
    if (isbf) {
      const u32* xr = (const u32*)((const u16*)x + base);
#pragma unroll
      for (int j = 0; j < 25; j++) {
        u32 d = xr[j];
        Af[tid][2 * j] = bf2f((u16)(d & 0xffffu));
        Af[tid][2 * j + 1] = bf2f((u16)(d >> 16));
      }
    } else {
      const float* xf = (const float*)x + base;
#pragma unroll
      for (int j = 0; j < 25; j++) {
        float2 d = *(const float2*)(xf + 2 * j);
        Af[tid][2 * j] = d.x;
        Af[tid][2 * j + 1] = d.y;
      }
    }
  }

  const int WOFF[3] = {W1F, W2F, W3F};
  const int BOFF[3] = {B1F, B2F, B3F};

  for (int l = 0; l < 3; l++) {
    __syncthreads();  // orders staging/scan writes of Af before GEMM reads
    const float* W = ws + WOFF[l];
    float acc[4][4][4];  // [off][c][r]: h = off*64+h0+c, t = t0*4+r
#pragma unroll
    for (int o = 0; o < 4; o++)
#pragma unroll
      for (int c = 0; c < 4; c++)
#pragma unroll
        for (int r = 0; r < 4; r++) acc[o][c][r] = 0.0f;

    const float* wp = W + h0;
    for (int s = 0; s < S_N; s++) {
      float4 av = *(const float4*)&Af[s][t0 * 4];  // broadcast groups, 16B aligned
      const float* wr = wp + s * H_N;
      float wv[4][4];
      *(float4*)&wv[0][0] = *(const float4*)(wr);
      *(float4*)&wv[1][0] = *(const float4*)(wr + 64);
      *(float4*)&wv[2][0] = *(const float4*)(wr + 128);
      *(float4*)&wv[3][0] = *(const float4*)(wr + 192);
      float a4[4] = {av.x, av.y, av.z, av.w};
#pragma unroll
      for (int o = 0; o < 4; o++)
#pragma unroll
        for (int c = 0; c < 4; c++)
#pragma unroll
          for (int r = 0; r < 4; r++)
            acc[o][c][r] = fmaf(a4[r], wv[o][c], acc[o][c][r]);  // ascending s chain
    }

    // scatter z to LDS (t = 50,51 hold garbage from unstaged Af tail; never read)
#pragma unroll
    for (int o = 0; o < 4; o++)
#pragma unroll
      for (int c = 0; c < 4; c++)
#pragma unroll
        for (int r = 0; r < 4; r++) {
          int t = t0 * 4 + r;
          if (t < 52) zs[t][o * 64 + h0 + c] = acc[o][c][r];
        }
    __syncthreads();

    // ---- LIF scan; thread = neuron h; replicate np fp32 elementwise exactly ----
    {
      const float bh = ws[BOFF[l] + tid];
      float uu = 0.f, vv = 0.f, ss = 0.f;
      for (int t = 0; t < T_N; t++) {
        float cur = fmaf(uu, 0.5f, zs[t][tid]) + bh;  // == (u*0.5 + z) + b exactly
        float t1 = vv * 0.75f;                        // np rounds v*0.75 once
        float volt = fmaf(t1, 1.0f - ss, cur);        // == t1*(1-s)+cur exactly ((1-s) in {0,1})
        float sp = (volt > 0.5f) ? 1.0f : 0.0f;
        uu = cur; vv = volt; ss = sp;
        Af[tid][t] = sp;  // next layer's input
      }
    }
  }

  // ---- layer 4 (H->2): ascending-h fp32 fma chain, then scan + output ----
  __syncthreads();
  if (tid < 2 * T_N) {
    const int t = tid >> 1, a = tid & 1;
    float az = 0.f;
    const float* w4p = ws + W4F + a;
    for (int h = 0; h < H_N; h++) az = fmaf(Af[h][t], w4p[2 * h], az);
    z4[t][a] = az;
  }
  __syncthreads();
  if (tid < 2) {
    const float bh = ws[B4F + tid];
    float uu = 0.f, vv = 0.f, ss = 0.f, sum = 0.f;
    for (int t = 0; t < T_N; t++) {
      float cur = fmaf(uu, 0.5f, z4[t][tid]) + bh;
      float t1 = vv * 0.75f;
      float volt = fmaf(t1, 1.0f - ss, cur);
      float sp = (volt > 0.5f) ? 1.0f : 0.0f;
      uu = cur; vv = volt; ss = sp;
      sum += sp;  // integer-valued, exact
    }
    float o = sum / 50.0f / 50.0f;  // two fp32 roundings, like np (sum/T)/T
    if (isbf) ((u16*)out)[b * 2 + tid] = f2bf(o);
    else ((float*)out)[b * 2 + tid] = o;
  }
}

extern "C" void kernel_launch(void* const* d_in, const int* in_sizes, int n_in,
                              void* d_out, int out_size, void* d_ws, size_t ws_size,
                              hipStream_t stream) {
  const void* x  = d_in[0];
  const void* w1 = d_in[1];
  const void* b1 = d_in[2];
  const void* w2 = d_in[3];
  const void* b2 = d_in[4];
  const void* w3 = d_in[5];
  const void* b3 = d_in[6];
  const void* w4 = d_in[7];
  const void* b4 = d_in[8];

  float* ws = (float*)d_ws;
  int* flag = (int*)d_ws + FLAGI;

  detect_dtype<<<1, 256, 0, stream>>>((const u16*)x, flag);
  convert_inputs<<<(CVT_N + 255) / 256, 256, 0, stream>>>(w1, w2, w3, w4, b1, b2, b3, b4, ws);
  snn_f32<<<B_N, 256, 0, stream>>>(x, ws, d_out);
}

// Round 4
// 1435.023 us; speedup vs baseline: 1.3906x; 1.3906x over previous
//
#include <hip/hip_runtime.h>

typedef unsigned short u16;
typedef unsigned int u32;

#define B_N 4096
#define S_N 256
#define T_N 50
#define H_N 256

// d_ws float-index layout (all fp32 after conversion)
#define W1F 0
#define W2F 65536
#define W3F 131072
#define W4F 196608
#define B1F 197120
#define B2F 197376
#define B3F 197632
#define B4F 197888
#define CVT_N 197890
#define FLAGI 198656   // int slot (aliased into the float ws)

__device__ __forceinline__ float bf2f(u16 h) { return __uint_as_float(((u32)h) << 16); }
__device__ __forceinline__ u16 f2bf(float f) {
  u32 x = __float_as_uint(f);
  return (u16)((x + 0x7fffu + ((x >> 16) & 1u)) >> 16);
}
__device__ __forceinline__ float ld_f(const void* p, size_t i, int isbf) {
  return isbf ? bf2f(((const u16*)p)[i]) : ((const float*)p)[i];
}

// bf16 x values are U(0,1): every even-index u16 <= 0x3F80 (~100%).
// fp32 x: even u16s are low mantissa halves: ~25% below 0x3F80.
__global__ void detect_dtype(const u16* __restrict__ x, int* __restrict__ flag) {
  __shared__ int cnt[256];
  int c = 0;
  for (int i = threadIdx.x; i < 4096; i += 256) c += (x[2 * i] <= 0x3F80u) ? 1 : 0;
  cnt[threadIdx.x] = c;
  __syncthreads();
  if (threadIdx.x == 0) {
    int tot = 0;
    for (int i = 0; i < 256; i++) tot += cnt[i];
    flag[0] = (tot > 3000) ? 1 : 0;
  }
}

// Up-convert all weights/biases to fp32 in ws (exact; bf16->fp32 is lossless).
__global__ void convert_inputs(const void* w1, const void* w2, const void* w3,
                               const void* w4, const void* b1, const void* b2,
                               const void* b3, const void* b4, float* __restrict__ ws) {
  const int isbf = ((const int*)ws)[FLAGI];
  int i = blockIdx.x * 256 + threadIdx.x;
  if (i >= CVT_N) return;
  float v;
  if (i < 196608) {
    const void* src = (i < 65536) ? w1 : (i < 131072 ? w2 : w3);
    v = ld_f(src, (size_t)(i & 65535), isbf);
  } else if (i < 197120) v = ld_f(w4, (size_t)(i - W4F), isbf);
  else if (i < 197376) v = ld_f(b1, (size_t)(i - B1F), isbf);
  else if (i < 197632) v = ld_f(b2, (size_t)(i - B2F), isbf);
  else if (i < 197888) v = ld_f(b3, (size_t)(i - B3F), isbf);
  else v = ld_f(b4, (size_t)(i - B4F), isbf);
  ws[i] = v;
}

// One block per batch element; thread = output neuron h; acc[50] in registers.
// GEMM chain per (t,h): fmaf(A[s][t], W[s][h], acc), s ascending from 0.0f —
// bit-identical to OpenBLAS sgemm's per-element serial vfmadd chain (K=256,
// single kc panel, vectorized over M/N only). LIF scan runs on the register
// accumulator directly; A[s][t] reads are wave-uniform LDS broadcasts.
__global__ __launch_bounds__(256, 3) void snn_f32(
    const void* __restrict__ x, const float* __restrict__ ws, void* __restrict__ out) {
  __shared__ float Af[S_N][52];   // A[s][t]: layer input (x, then spikes); 208 B rows (16B-aligned)
  __shared__ float z4[T_N][2];

  const int b = blockIdx.x;
  const int tid = threadIdx.x;
  const int isbf = ((const int*)ws)[FLAGI];

  // ---- stage x -> Af[s][t] (thread = source row s; 50 contiguous elems) ----
  {
    const size_t base = ((size_t)b * S_N + tid) * T_N;
    if (isbf) {
      const u32* xr = (const u32*)((const u16*)x + base);
#pragma unroll
      for (int j = 0; j < 25; j++) {
        u32 d = xr[j];
        Af[tid][2 * j] = bf2f((u16)(d & 0xffffu));
        Af[tid][2 * j + 1] = bf2f((u16)(d >> 16));
      }
    } else {
      const float* xf = (const float*)x + base;
#pragma unroll
      for (int j = 0; j < 25; j++) {
        float2 d = *(const float2*)(xf + 2 * j);
        Af[tid][2 * j] = d.x;
        Af[tid][2 * j + 1] = d.y;
      }
    }
  }

  const int WOFF[3] = {W1F, W2F, W3F};
  const int BOFF[3] = {B1F, B2F, B3F};

  for (int l = 0; l < 3; l++) {
    __syncthreads();  // A writes (staging / prev scan) visible before GEMM reads
    const float* W = ws + WOFF[l] + tid;  // column h = tid; coalesced across lanes

    float acc[T_N];
#pragma unroll
    for (int t = 0; t < T_N; t++) acc[t] = 0.0f;

    for (int s = 0; s < S_N; s++) {
      const float w = W[s << 8];                       // W[s][h], L2-resident
      const float4* ar = (const float4*)&Af[s][0];     // wave-uniform -> LDS broadcast
      float4 av[12];
#pragma unroll
      for (int j = 0; j < 12; j++) av[j] = ar[j];
      float2 at = *(const float2*)&Af[s][48];
#pragma unroll
      for (int j = 0; j < 12; j++) {
        acc[4 * j + 0] = fmaf(av[j].x, w, acc[4 * j + 0]);
        acc[4 * j + 1] = fmaf(av[j].y, w, acc[4 * j + 1]);
        acc[4 * j + 2] = fmaf(av[j].z, w, acc[4 * j + 2]);
        acc[4 * j + 3] = fmaf(av[j].w, w, acc[4 * j + 3]);
      }
      acc[48] = fmaf(at.x, w, acc[48]);
      acc[49] = fmaf(at.y, w, acc[49]);
    }
    __syncthreads();  // all waves done reading Af before scan overwrites it

    // ---- LIF scan on registers; replicate np fp32 elementwise ops exactly ----
    {
      const float bh = ws[BOFF[l] + tid];
      float uu = 0.f, vv = 0.f, ss = 0.f;
#pragma unroll
      for (int t = 0; t < T_N; t++) {
        float cur = fmaf(uu, 0.5f, acc[t]) + bh;  // == (u*0.5 + z) + b exactly
        float t1 = vv * 0.75f;                    // np rounds v*0.75 once
        float volt = fmaf(t1, 1.0f - ss, cur);    // == t1*(1-s)+cur exactly ((1-s) in {0,1})
        float sp = (volt > 0.5f) ? 1.0f : 0.0f;
        uu = cur; vv = volt; ss = sp;
        Af[tid][t] = sp;  // next layer's input row
      }
    }
  }

  // ---- layer 4 (H->2): ascending-h fp32 fma chain, then scan + output ----
  __syncthreads();
  if (tid < 2 * T_N) {
    const int t = tid >> 1, a = tid & 1;
    float az = 0.f;
    const float* w4p = ws + W4F + a;
    for (int h = 0; h < H_N; h++) az = fmaf(Af[h][t], w4p[2 * h], az);
    z4[t][a] = az;
  }
  __syncthreads();
  if (tid < 2) {
    const float bh = ws[B4F + tid];
    float uu = 0.f, vv = 0.f, ss = 0.f, sum = 0.f;
    for (int t = 0; t < T_N; t++) {
      float cur = fmaf(uu, 0.5f, z4[t][tid]) + bh;
      float t1 = vv * 0.75f;
      float volt = fmaf(t1, 1.0f - ss, cur);
      float sp = (volt > 0.5f) ? 1.0f : 0.0f;
      uu = cur; vv = volt; ss = sp;
      sum += sp;  // integer-valued, exact
    }
    float o = sum / 50.0f / 50.0f;  // two fp32 roundings, like np (sum/T)/T
    if (isbf) ((u16*)out)[b * 2 + tid] = f2bf(o);
    else ((float*)out)[b * 2 + tid] = o;
  }
}

extern "C" void kernel_launch(void* const* d_in, const int* in_sizes, int n_in,
                              void* d_out, int out_size, void* d_ws, size_t ws_size,
                              hipStream_t stream) {
  const void* x  = d_in[0];
  const void* w1 = d_in[1];
  const void* b1 = d_in[2];
  const void* w2 = d_in[3];
  const void* b2 = d_in[4];
  const void* w3 = d_in[5];
  const void* b3 = d_in[6];
  const void* w4 = d_in[7];
  const void* b4 = d_in[8];

  float* ws = (float*)d_ws;
  int* flag = (int*)d_ws + FLAGI;

  detect_dtype<<<1, 256, 0, stream>>>((const u16*)x, flag);
  convert_inputs<<<(CVT_N + 255) / 256, 256, 0, stream>>>(w1, w2, w3, w4, b1, b2, b3, b4, ws);
  snn_f32<<<B_N, 256, 0, stream>>>(x, ws, d_out);
}